// Round 4
// baseline (533.912 us; speedup 1.0000x reference)
//
#include <hip/hip_runtime.h>
#include <hip/hip_bf16.h>
#include <stdint.h>

// DepthSepConv2d: x(32,256,56,56) -> dw3x3(reflect) -> BN1 -> ReLU -> pw 256->512 -> BN2 -> ReLU
// Pipeline: K1 stats1 | K2 finalize1 + w->bf16 | K3 conv+BN1+ReLU -> y_t[b][hw][c] bf16
//           K4 MFMA GEMM (z fp32 -> d_out, BN2 stats fused) | K4b finalize2 | K5 BN2+ReLU in-place
// dw_b / pw_b are per-channel constants inside their BN -> cancel exactly; skipped.

#define CIN   256
#define COUT  512
#define BATCH 32
#define HH    56
#define WWID  56
#define HWSZ  3136
#define NHWF  100352.0f
#define EPSV  1e-5f

typedef __bf16 bf16;
typedef __bf16 bf16x8 __attribute__((ext_vector_type(8)));
typedef float  f32x4  __attribute__((ext_vector_type(4)));

// ws layout (bytes)
#define WS_STATS1   0        // 512 f: sum[256], sumsq[256]
#define WS_SCALE1   2048     // 256 f
#define WS_SHIFT1   3072     // 256 f
#define WS_STATS2   4096     // 1024 f: sum[512], sumsq[512]
#define WS_SCALE2   8192     // 512 f
#define WS_SHIFT2   10240    // 512 f
#define WS_WBF      16384    // 512*256 bf16 = 256 KiB
#define WS_YT       278528   // 32*3136*256 bf16 = 51.4 MB

__device__ __forceinline__ void gload16(const void* g, void* l) {
  __builtin_amdgcn_global_load_lds((const __attribute__((address_space(1))) void*)g,
                                   (__attribute__((address_space(3))) void*)l, 16, 0, 0);
}

// ---------------- K1: depthwise conv (no bias) -> per-channel sum/sumsq ----------------
__global__ __launch_bounds__(256) void k1_dwstats(const float* __restrict__ x,
                                                  const float* __restrict__ dww,
                                                  float* __restrict__ stats1) {
  __shared__ float plane[HWSZ];
  __shared__ float red[8];
  int bid = blockIdx.x;
  int c = bid & (CIN - 1);
  int b = bid >> 8;
  const float4* xp4 = (const float4*)(x + ((size_t)(b * CIN + c)) * HWSZ);
  float4* pl4 = (float4*)plane;
  for (int i = threadIdx.x; i < HWSZ / 4; i += 256) pl4[i] = xp4[i];
  float w9[9];
#pragma unroll
  for (int q = 0; q < 9; ++q) w9[q] = dww[c * 9 + q];
  __syncthreads();
  float s = 0.f, sq = 0.f;
  for (int p = threadIdx.x; p < HWSZ; p += 256) {
    int h = p / WWID;
    int w = p - h * WWID;
    float acc = 0.f;
#pragma unroll
    for (int dy = 0; dy < 3; ++dy) {
      int hh = h - 1 + dy;
      hh = hh < 0 ? 1 : (hh > 55 ? 54 : hh);   // reflect pad=1
#pragma unroll
      for (int dx = 0; dx < 3; ++dx) {
        int ww2 = w - 1 + dx;
        ww2 = ww2 < 0 ? 1 : (ww2 > 55 ? 54 : ww2);
        acc += w9[dy * 3 + dx] * plane[hh * WWID + ww2];
      }
    }
    s += acc; sq += acc * acc;
  }
#pragma unroll
  for (int m = 1; m < 64; m <<= 1) { s += __shfl_xor(s, m); sq += __shfl_xor(sq, m); }
  int wv = threadIdx.x >> 6;
  if ((threadIdx.x & 63) == 0) { red[wv] = s; red[4 + wv] = sq; }
  __syncthreads();
  if (threadIdx.x == 0) {
    atomicAdd(&stats1[c],        red[0] + red[1] + red[2] + red[3]);
    atomicAdd(&stats1[CIN + c],  red[4] + red[5] + red[6] + red[7]);
  }
}

// ---------------- K2: finalize BN1 + convert pw_w to bf16 ----------------
__global__ __launch_bounds__(256) void k2_finalize1(const float* __restrict__ stats1,
                                                    const float* __restrict__ g1,
                                                    const float* __restrict__ b1,
                                                    const float* __restrict__ pww,
                                                    float* __restrict__ scale1,
                                                    float* __restrict__ shift1,
                                                    bf16* __restrict__ wbf) {
  int blk = blockIdx.x, t = threadIdx.x;
  if (blk == 0) {
    float mean = stats1[t] * (1.0f / NHWF);
    float var  = stats1[CIN + t] * (1.0f / NHWF) - mean * mean;
    float sc = g1[t] * rsqrtf(var + EPSV);
    scale1[t] = sc;
    shift1[t] = b1[t] - mean * sc;
  } else {
    int o = blk - 1;
    wbf[o * CIN + t] = (bf16)pww[o * CIN + t];
  }
}

// ---------------- K3: conv + BN1 + ReLU -> y_t[b][hw][c] bf16 (transposed) ----------------
__global__ __launch_bounds__(256) void k3_normT(const float* __restrict__ x,
                                                const float* __restrict__ dww,
                                                const float* __restrict__ scale1,
                                                const float* __restrict__ shift1,
                                                bf16* __restrict__ yt) {
  __shared__ float xt[64][3][58];
  __shared__ __align__(16) bf16 outt[56][64];
  int bid = blockIdx.x;
  int cg = bid & 3;
  int h  = (bid >> 2) % 56;
  int b  = bid / 224;
  int c0 = cg * 64;
  int hr0 = (h == 0) ? 1 : h - 1;
  int hr2 = (h == 55) ? 54 : h + 1;
  for (int idx = threadIdx.x; idx < 64 * 3 * 56; idx += 256) {
    int c = idx / 168;
    int rem = idx - c * 168;
    int r = rem / 56;
    int w = rem - r * 56;
    int hr = (r == 0) ? hr0 : ((r == 1) ? h : hr2);
    xt[c][r][w + 1] = x[((size_t)((b * CIN + c0 + c) * HH + hr)) * WWID + w];
  }
  __syncthreads();
  if (threadIdx.x < 192) {
    int c = threadIdx.x / 3, r = threadIdx.x % 3;
    xt[c][r][0]  = xt[c][r][2];   // w=-1 -> x[1]
    xt[c][r][57] = xt[c][r][55];  // w=56 -> x[54]
  }
  __syncthreads();
  int c  = threadIdx.x >> 2;
  int wq = threadIdx.x & 3;
  float w9[9];
#pragma unroll
  for (int q = 0; q < 9; ++q) w9[q] = dww[(c0 + c) * 9 + q];
  float sc = scale1[c0 + c], sh = shift1[c0 + c];
  for (int w = wq; w < 56; w += 4) {
    float acc = 0.f;
#pragma unroll
    for (int r = 0; r < 3; ++r) {
      const float* row = &xt[c][r][w];   // logical w-1+dx stored at w+dx
      acc += w9[r * 3 + 0] * row[0] + w9[r * 3 + 1] * row[1] + w9[r * 3 + 2] * row[2];
    }
    float v = fmaxf(acc * sc + sh, 0.f);
    outt[w][c] = (bf16)v;
  }
  __syncthreads();
  for (int idx = threadIdx.x; idx < 56 * 8; idx += 256) {
    int w = idx >> 3, part = idx & 7;
    uint4 v = *(const uint4*)(&outt[w][part * 8]);
    *(uint4*)(yt + ((size_t)(b * HWSZ + h * WWID + w)) * CIN + c0 + part * 8) = v;
  }
}

// ---------------- K4: bf16 MFMA GEMM: z[b][o][p] = sum_c W[o][c]*y_t[b][p][c] ----------------
// tile 128(o) x 64(p), BK=32, 4 waves (2x2), each wave 64x32 = 4x2 16x16 frags.
// LDS rows are 64B; chunk-XOR swizzle (c ^ ((row>>1)&3)) applied on the GLOBAL source
// (global_load_lds writes linearly) and on the ds_read side -> 2-way max conflicts.
__global__ __launch_bounds__(256) void k4_gemm(const bf16* __restrict__ wbf,
                                               const bf16* __restrict__ yt,
                                               float* __restrict__ zout,
                                               float* __restrict__ stats2) {
  __shared__ __align__(16) unsigned char Als[8192];   // [128][32] bf16, swizzled
  __shared__ __align__(16) unsigned char Bls[4096];   // [64][32]  bf16, swizzled
  __shared__ float sl[256];                           // sum[128], sumsq[128]
  int bid = blockIdx.x;
  int mt = bid & 3;
  int nt = (bid >> 2) % 49;
  int b  = bid / 196;
  int tid = threadIdx.x;
  int wv = tid >> 6, l = tid & 63;
  f32x4 acc[4][2];
#pragma unroll
  for (int mi = 0; mi < 4; ++mi)
#pragma unroll
    for (int ni = 0; ni < 2; ++ni) acc[mi][ni] = (f32x4){0.f, 0.f, 0.f, 0.f};
  const char* wb = (const char*)wbf;
  const char* yb = (const char*)(yt + ((size_t)b * HWSZ + nt * 64) * CIN);

  for (int k0 = 0; k0 < 256; k0 += 32) {
    // stage A: 512 x 16B chunks, linear LDS dest, pre-swizzled global source
#pragma unroll
    for (int i = 0; i < 2; ++i) {
      int q = i * 256 + wv * 64 + l;
      int row = q >> 2, pp = q & 3;
      int cc = pp ^ ((row >> 1) & 3);
      gload16(wb + ((size_t)(mt * 128 + row) * 256 + k0) * 2 + cc * 16,
              Als + i * 4096 + wv * 1024);
    }
    {
      int q = wv * 64 + l;
      int row = q >> 2, pp = q & 3;
      int cc = pp ^ ((row >> 1) & 3);
      gload16(yb + ((size_t)row * 256 + k0) * 2 + cc * 16, Bls + wv * 1024);
    }
    __syncthreads();
    bf16x8 af[4], bfr[2];
#pragma unroll
    for (int mi = 0; mi < 4; ++mi) {
      int row = (wv >> 1) * 64 + mi * 16 + (l & 15);
      int off = row * 64 + (((l >> 4) ^ ((row >> 1) & 3)) << 4);
      af[mi] = *(const bf16x8*)(Als + off);
    }
#pragma unroll
    for (int ni = 0; ni < 2; ++ni) {
      int row = (wv & 1) * 32 + ni * 16 + (l & 15);
      int off = row * 64 + (((l >> 4) ^ ((row >> 1) & 3)) << 4);
      bfr[ni] = *(const bf16x8*)(Bls + off);
    }
#pragma unroll
    for (int mi = 0; mi < 4; ++mi)
#pragma unroll
      for (int ni = 0; ni < 2; ++ni)
        acc[mi][ni] = __builtin_amdgcn_mfma_f32_16x16x32_bf16(af[mi], bfr[ni], acc[mi][ni], 0, 0, 0);
    __syncthreads();
  }

  // epilogue: write z (fp32) + fused BN2 partial stats
  int p_base = nt * 64 + (wv & 1) * 32;
  int o_base = mt * 128 + (wv >> 1) * 64;
#pragma unroll
  for (int mi = 0; mi < 4; ++mi)
#pragma unroll
    for (int ni = 0; ni < 2; ++ni)
#pragma unroll
      for (int j = 0; j < 4; ++j) {
        int o = o_base + mi * 16 + (l >> 4) * 4 + j;
        int p = p_base + ni * 16 + (l & 15);
        zout[((size_t)(b * COUT + o)) * HWSZ + p] = acc[mi][ni][j];
      }
  sl[tid] = 0.f;
  __syncthreads();
#pragma unroll
  for (int mi = 0; mi < 4; ++mi)
#pragma unroll
    for (int j = 0; j < 4; ++j) {
      float s  = acc[mi][0][j] + acc[mi][1][j];
      float q2 = acc[mi][0][j] * acc[mi][0][j] + acc[mi][1][j] * acc[mi][1][j];
#pragma unroll
      for (int m = 1; m < 16; m <<= 1) { s += __shfl_xor(s, m); q2 += __shfl_xor(q2, m); }
      if ((l & 15) == 0) {
        int ol = (wv >> 1) * 64 + mi * 16 + (l >> 4) * 4 + j;
        atomicAdd(&sl[ol], s);
        atomicAdd(&sl[128 + ol], q2);
      }
    }
  __syncthreads();
  {
    int which = tid >> 7, i = tid & 127;
    atomicAdd(&stats2[which * COUT + mt * 128 + i], sl[tid]);
  }
}

// ---------------- K4b: finalize BN2 ----------------
__global__ void k4b_finalize2(const float* __restrict__ stats2,
                              const float* __restrict__ g2, const float* __restrict__ b2,
                              float* __restrict__ scale2, float* __restrict__ shift2) {
  int t = threadIdx.x;  // 512
  float mean = stats2[t] * (1.0f / NHWF);
  float var  = stats2[COUT + t] * (1.0f / NHWF) - mean * mean;
  float sc = g2[t] * rsqrtf(var + EPSV);
  scale2[t] = sc;
  shift2[t] = b2[t] - mean * sc;
}

// ---------------- K5: BN2 + ReLU, in place on d_out ----------------
__global__ __launch_bounds__(256) void k5_bn2(float* __restrict__ z,
                                              const float* __restrict__ scale2,
                                              const float* __restrict__ shift2) {
  const int n4 = (BATCH * COUT * HWSZ) / 4;  // 12845056
  int stride = gridDim.x * blockDim.x;
  float4* z4 = (float4*)z;
  for (int i = blockIdx.x * blockDim.x + threadIdx.x; i < n4; i += stride) {
    int c = (i / 784) % COUT;   // 784 float4 per (b,o) plane
    float s = scale2[c], sh = shift2[c];
    float4 v = z4[i];
    v.x = fmaxf(v.x * s + sh, 0.f);
    v.y = fmaxf(v.y * s + sh, 0.f);
    v.z = fmaxf(v.z * s + sh, 0.f);
    v.w = fmaxf(v.w * s + sh, 0.f);
    z4[i] = v;
  }
}

extern "C" void kernel_launch(void* const* d_in, const int* in_sizes, int n_in,
                              void* d_out, int out_size, void* d_ws, size_t ws_size,
                              hipStream_t stream) {
  const float* x   = (const float*)d_in[0];
  const float* dww = (const float*)d_in[1];
  // d_in[2] = dw_b : cancels inside BN1 -> unused
  const float* g1  = (const float*)d_in[3];
  const float* b1  = (const float*)d_in[4];
  const float* pww = (const float*)d_in[5];
  // d_in[6] = pw_b : cancels inside BN2 -> unused
  const float* g2  = (const float*)d_in[7];
  const float* b2  = (const float*)d_in[8];
  float* out = (float*)d_out;
  char* ws = (char*)d_ws;
  float* stats1 = (float*)(ws + WS_STATS1);
  float* scale1 = (float*)(ws + WS_SCALE1);
  float* shift1 = (float*)(ws + WS_SHIFT1);
  float* stats2 = (float*)(ws + WS_STATS2);
  float* scale2 = (float*)(ws + WS_SCALE2);
  float* shift2 = (float*)(ws + WS_SHIFT2);
  bf16* wbf = (bf16*)(ws + WS_WBF);
  bf16* yt  = (bf16*)(ws + WS_YT);

  hipMemsetAsync(d_ws, 0, 8192, stream);  // zero stats1 + stats2
  k1_dwstats<<<BATCH * CIN, 256, 0, stream>>>(x, dww, stats1);
  k2_finalize1<<<513, 256, 0, stream>>>(stats1, g1, b1, pww, scale1, shift1, wbf);
  k3_normT<<<BATCH * 56 * 4, 256, 0, stream>>>(x, dww, scale1, shift1, yt);
  k4_gemm<<<4 * 49 * BATCH, 256, 0, stream>>>(wbf, yt, out, stats2);
  k4b_finalize2<<<1, 512, 0, stream>>>(stats2, g2, b2, scale2, shift2);
  k5_bn2<<<2048, 256, 0, stream>>>(out, scale2, shift2);
}

// Round 5
// 502.603 us; speedup vs baseline: 1.0623x; 1.0623x over previous
//
#include <hip/hip_runtime.h>
#include <hip/hip_bf16.h>
#include <stdint.h>

// DepthSepConv2d: x(32,256,56,56) -> dw3x3(reflect) -> BN1 -> ReLU -> pw 256->512 -> BN2 -> ReLU
// R4 pipeline: K1 stats1 | K2 finalize1 + w->bf16 | K3 conv+BN1+ReLU -> y_t[r][c] bf16
//   K4 MFMA GEMM 128x128 BK=64 (z -> bf16 ws, BN2 stats fp32-exact fused, XCD swizzle)
//   K5 BN2 finalize (per-block) + apply + ReLU: zbf16 -> out fp32
// dw_b / pw_b cancel exactly inside their BN -> skipped.

#define CIN   256
#define COUT  512
#define BATCH 32
#define HH    56
#define WWID  56
#define HWSZ  3136
#define NTOT  100352        // BATCH*HWSZ, flat GEMM N
#define NHWF  100352.0f
#define EPSV  1e-5f

typedef __bf16 bf16;
typedef __bf16 bf16x8 __attribute__((ext_vector_type(8)));
typedef float  f32x4  __attribute__((ext_vector_type(4)));

// ws layout (bytes)
#define WS_STATS1   0          // 512 f: sum[256], sumsq[256]
#define WS_SCALE1   2048       // 256 f
#define WS_SHIFT1   3072       // 256 f
#define WS_STATS2   4096       // 1024 f: sum[512], sumsq[512]  (ends 8192)
#define WS_WBF      16384      // 512*256 bf16 = 256 KiB (ends 278528)
#define WS_YT       278528     // 100352*256 bf16 = 51,380,224 B (ends 51,658,752)
#define WS_ZBF      51658752   // 32*512*3136 bf16 = 102,760,448 B (ends 154,419,200)

__device__ __forceinline__ void gload16(const void* g, void* l) {
  __builtin_amdgcn_global_load_lds((const __attribute__((address_space(1))) void*)g,
                                   (__attribute__((address_space(3))) void*)l, 16, 0, 0);
}
__device__ __forceinline__ float bfu(unsigned int u16) {
  unsigned int x = u16 << 16;
  return __builtin_bit_cast(float, x);
}

// ---------------- K1: depthwise conv (no bias) -> per-channel sum/sumsq ----------------
__global__ __launch_bounds__(256) void k1_dwstats(const float* __restrict__ x,
                                                  const float* __restrict__ dww,
                                                  float* __restrict__ stats1) {
  __shared__ float plane[HWSZ];
  __shared__ float red[8];
  int bid = blockIdx.x;
  int c = bid & (CIN - 1);
  int b = bid >> 8;
  const float4* xp4 = (const float4*)(x + ((size_t)(b * CIN + c)) * HWSZ);
  float4* pl4 = (float4*)plane;
  for (int i = threadIdx.x; i < HWSZ / 4; i += 256) pl4[i] = xp4[i];
  float w9[9];
#pragma unroll
  for (int q = 0; q < 9; ++q) w9[q] = dww[c * 9 + q];
  __syncthreads();
  float s = 0.f, sq = 0.f;
  for (int p = threadIdx.x; p < HWSZ; p += 256) {
    int h = p / WWID;
    int w = p - h * WWID;
    float acc = 0.f;
#pragma unroll
    for (int dy = 0; dy < 3; ++dy) {
      int hh = h - 1 + dy;
      hh = hh < 0 ? 1 : (hh > 55 ? 54 : hh);   // reflect pad=1
#pragma unroll
      for (int dx = 0; dx < 3; ++dx) {
        int ww2 = w - 1 + dx;
        ww2 = ww2 < 0 ? 1 : (ww2 > 55 ? 54 : ww2);
        acc += w9[dy * 3 + dx] * plane[hh * WWID + ww2];
      }
    }
    s += acc; sq += acc * acc;
  }
#pragma unroll
  for (int m = 1; m < 64; m <<= 1) { s += __shfl_xor(s, m); sq += __shfl_xor(sq, m); }
  int wv = threadIdx.x >> 6;
  if ((threadIdx.x & 63) == 0) { red[wv] = s; red[4 + wv] = sq; }
  __syncthreads();
  if (threadIdx.x == 0) {
    atomicAdd(&stats1[c],        red[0] + red[1] + red[2] + red[3]);
    atomicAdd(&stats1[CIN + c],  red[4] + red[5] + red[6] + red[7]);
  }
}

// ---------------- K2: finalize BN1 + convert pw_w to bf16 ----------------
__global__ __launch_bounds__(256) void k2_finalize1(const float* __restrict__ stats1,
                                                    const float* __restrict__ g1,
                                                    const float* __restrict__ b1,
                                                    const float* __restrict__ pww,
                                                    float* __restrict__ scale1,
                                                    float* __restrict__ shift1,
                                                    bf16* __restrict__ wbf) {
  int blk = blockIdx.x, t = threadIdx.x;
  if (blk == 0) {
    float mean = stats1[t] * (1.0f / NHWF);
    float var  = stats1[CIN + t] * (1.0f / NHWF) - mean * mean;
    float sc = g1[t] * rsqrtf(var + EPSV);
    scale1[t] = sc;
    shift1[t] = b1[t] - mean * sc;
  } else {
    int o = blk - 1;
    wbf[o * CIN + t] = (bf16)pww[o * CIN + t];
  }
}

// ---------------- K3: conv + BN1 + ReLU -> y_t[r = b*HWSZ+hw][c] bf16 (transposed) ----------------
__global__ __launch_bounds__(256) void k3_normT(const float* __restrict__ x,
                                                const float* __restrict__ dww,
                                                const float* __restrict__ scale1,
                                                const float* __restrict__ shift1,
                                                bf16* __restrict__ yt) {
  __shared__ float xt[64][3][58];
  __shared__ __align__(16) bf16 outt[56][64];
  int bid = blockIdx.x;
  int cg = bid & 3;
  int h  = (bid >> 2) % 56;
  int b  = bid / 224;
  int c0 = cg * 64;
  int hr0 = (h == 0) ? 1 : h - 1;
  int hr2 = (h == 55) ? 54 : h + 1;
  for (int idx = threadIdx.x; idx < 64 * 3 * 56; idx += 256) {
    int c = idx / 168;
    int rem = idx - c * 168;
    int r = rem / 56;
    int w = rem - r * 56;
    int hr = (r == 0) ? hr0 : ((r == 1) ? h : hr2);
    xt[c][r][w + 1] = x[((size_t)((b * CIN + c0 + c) * HH + hr)) * WWID + w];
  }
  __syncthreads();
  if (threadIdx.x < 192) {
    int c = threadIdx.x / 3, r = threadIdx.x % 3;
    xt[c][r][0]  = xt[c][r][2];   // w=-1 -> x[1]
    xt[c][r][57] = xt[c][r][55];  // w=56 -> x[54]
  }
  __syncthreads();
  int c  = threadIdx.x >> 2;
  int wq = threadIdx.x & 3;
  float w9[9];
#pragma unroll
  for (int q = 0; q < 9; ++q) w9[q] = dww[(c0 + c) * 9 + q];
  float sc = scale1[c0 + c], sh = shift1[c0 + c];
  for (int w = wq; w < 56; w += 4) {
    float acc = 0.f;
#pragma unroll
    for (int r = 0; r < 3; ++r) {
      const float* row = &xt[c][r][w];   // logical w-1+dx stored at w+dx
      acc += w9[r * 3 + 0] * row[0] + w9[r * 3 + 1] * row[1] + w9[r * 3 + 2] * row[2];
    }
    float v = fmaxf(acc * sc + sh, 0.f);
    outt[w][c] = (bf16)v;
  }
  __syncthreads();
  for (int idx = threadIdx.x; idx < 56 * 8; idx += 256) {
    int w = idx >> 3, part = idx & 7;
    uint4 v = *(const uint4*)(&outt[w][part * 8]);
    *(uint4*)(yt + ((size_t)(b * HWSZ + h * WWID + w)) * CIN + c0 + part * 8) = v;
  }
}

// ---------------- K4: bf16 MFMA GEMM: z[o][r] = sum_c W[o][c]*y_t[r][c] ----------------
// Tile 128(M=o) x 128(N=r), BK=64. 4 waves 2x2; wave sub-tile 64x64 = 4x4 16x16 frags.
// LDS rows 128 B; chunk-XOR swizzle (ck ^ (row&7)) on pre-swizzled global source + ds_read.
// Epilogue: BN2 stats from fp32 acc (exact), then LDS-transpose -> bf16 z, 16B stores.
// XCD-chunked blockIdx swizzle (nwg=3136, %8==0).
__global__ __launch_bounds__(256) void k4_gemm(const bf16* __restrict__ wbf,
                                               const bf16* __restrict__ yt,
                                               bf16* __restrict__ zbf,
                                               float* __restrict__ stats2) {
  __shared__ __align__(16) unsigned char LDSBUF[32768];  // A[0:16K) B[16K:32K); reused as z[128][128] bf16
  __shared__ float sl[256];                              // sum[128], sumsq[128]
  unsigned char* Als = LDSBUF;
  unsigned char* Bls = LDSBUF + 16384;
  int wg = blockIdx.x;
  int newid = (wg & 7) * 392 + (wg >> 3);   // XCD-chunked swizzle (bijective, 3136%8==0)
  int mt    = newid & 3;                    // 4 M-tiles of 128 over COUT=512
  int ntile = newid >> 2;                   // 784 N-tiles of 128 over NTOT=100352
  int tid = threadIdx.x;
  int wv = tid >> 6, l = tid & 63;
  int wm = wv >> 1, wn = wv & 1;
  f32x4 acc[4][4];
#pragma unroll
  for (int mi = 0; mi < 4; ++mi)
#pragma unroll
    for (int ni = 0; ni < 4; ++ni) acc[mi][ni] = (f32x4){0.f, 0.f, 0.f, 0.f};
  const char* wb = (const char*)wbf;                                   // W [512][256]
  const char* yb = (const char*)yt + (size_t)ntile * 128 * CIN * 2;    // y_t [128 rows][256]

  for (int k0 = 0; k0 < 256; k0 += 64) {
    // stage A+B: each 128 rows x 128 B = 1024 x 16B chunks; linear LDS dest, swizzled global src
#pragma unroll
    for (int i = 0; i < 4; ++i) {
      int q = i * 256 + wv * 64 + l;
      int row = q >> 3, pp = q & 7;
      int cc = pp ^ (row & 7);
      gload16(wb + ((size_t)(mt * 128 + row) * CIN + k0) * 2 + cc * 16,
              Als + i * 4096 + wv * 1024);
      gload16(yb + ((size_t)row * CIN + k0) * 2 + cc * 16,
              Bls + i * 4096 + wv * 1024);
    }
    __syncthreads();
#pragma unroll
    for (int kk = 0; kk < 2; ++kk) {
      bf16x8 af[4], bfr[4];
#pragma unroll
      for (int mi = 0; mi < 4; ++mi) {
        int row = wm * 64 + mi * 16 + (l & 15);
        int ck = kk * 4 + (l >> 4);
        af[mi] = *(const bf16x8*)(Als + row * 128 + ((ck ^ (row & 7)) << 4));
      }
#pragma unroll
      for (int ni = 0; ni < 4; ++ni) {
        int row = wn * 64 + ni * 16 + (l & 15);
        int ck = kk * 4 + (l >> 4);
        bfr[ni] = *(const bf16x8*)(Bls + row * 128 + ((ck ^ (row & 7)) << 4));
      }
#pragma unroll
      for (int mi = 0; mi < 4; ++mi)
#pragma unroll
        for (int ni = 0; ni < 4; ++ni)
          acc[mi][ni] = __builtin_amdgcn_mfma_f32_16x16x32_bf16(af[mi], bfr[ni], acc[mi][ni], 0, 0, 0);
    }
    __syncthreads();
  }

  // --- BN2 partial stats from fp32 acc (exact w.r.t. bf16-z quantization) ---
  sl[tid] = 0.f;
  __syncthreads();
#pragma unroll
  for (int mi = 0; mi < 4; ++mi)
#pragma unroll
    for (int j = 0; j < 4; ++j) {
      float s = 0.f, q2 = 0.f;
#pragma unroll
      for (int ni = 0; ni < 4; ++ni) {
        float v = acc[mi][ni][j];
        s += v; q2 += v * v;
      }
#pragma unroll
      for (int m = 1; m < 16; m <<= 1) { s += __shfl_xor(s, m); q2 += __shfl_xor(q2, m); }
      if ((l & 15) == 0) {
        int ol = wm * 64 + mi * 16 + (l >> 4) * 4 + j;
        atomicAdd(&sl[ol], s);
        atomicAdd(&sl[128 + ol], q2);
      }
    }
  __syncthreads();
  {
    int which = tid >> 7, i = tid & 127;
    atomicAdd(&stats2[which * COUT + mt * 128 + i], sl[tid]);
  }

  // --- transpose acc -> LDS [o_local 128][r_local 128] bf16, then 16B coalesced stores ---
  bf16* zl = (bf16*)LDSBUF;
#pragma unroll
  for (int mi = 0; mi < 4; ++mi)
#pragma unroll
    for (int ni = 0; ni < 4; ++ni)
#pragma unroll
      for (int j = 0; j < 4; ++j) {
        int ol = wm * 64 + mi * 16 + (l >> 4) * 4 + j;
        int rl = wn * 64 + ni * 16 + (l & 15);
        zl[ol * 128 + rl] = (bf16)acc[mi][ni][j];
      }
  __syncthreads();
  size_t rbase = (size_t)ntile * 128;
  for (int ch = tid; ch < 2048; ch += 256) {      // 128 o x 16 (8-elem chunks)
    int ol = ch >> 4, r8 = ch & 15;
    size_t r = rbase + (size_t)r8 * 8;
    int b  = (int)(r / HWSZ);                     // 8-runs never straddle b (HWSZ%8==0)
    int hw = (int)(r - (size_t)b * HWSZ);
    int o  = mt * 128 + ol;
    *(uint4*)(zbf + ((size_t)(b * COUT + o)) * HWSZ + hw) = *(const uint4*)(zl + ol * 128 + r8 * 8);
  }
}

// ---------------- K5: BN2 finalize (per-block) + apply + ReLU: zbf -> out fp32 ----------------
__global__ __launch_bounds__(256) void k5_bn2(const bf16* __restrict__ zbf,
                                              const float* __restrict__ stats2,
                                              const float* __restrict__ g2,
                                              const float* __restrict__ b2,
                                              float* __restrict__ out) {
  __shared__ float s2l[COUT], sh2l[COUT];
  for (int c = threadIdx.x; c < COUT; c += 256) {
    float mean = stats2[c] * (1.0f / NHWF);
    float var  = stats2[COUT + c] * (1.0f / NHWF) - mean * mean;
    float sc = g2[c] * rsqrtf(var + EPSV);
    s2l[c]  = sc;
    sh2l[c] = b2[c] - mean * sc;
  }
  __syncthreads();
  const int n8 = BATCH * COUT * HWSZ / 8;   // 6,422,528 chunks of 8 bf16
  int stride = gridDim.x * blockDim.x;
  const uint4* z4 = (const uint4*)zbf;
  for (int i = blockIdx.x * blockDim.x + threadIdx.x; i < n8; i += stride) {
    int c = (i / 392) & (COUT - 1);          // 392 chunks per (b,c) plane
    float s = s2l[c], sh = sh2l[c];
    uint4 v = z4[i];
    float4 o1, o2;
    o1.x = fmaxf(bfu(v.x & 0xffffu) * s + sh, 0.f);
    o1.y = fmaxf(bfu(v.x >> 16)     * s + sh, 0.f);
    o1.z = fmaxf(bfu(v.y & 0xffffu) * s + sh, 0.f);
    o1.w = fmaxf(bfu(v.y >> 16)     * s + sh, 0.f);
    o2.x = fmaxf(bfu(v.z & 0xffffu) * s + sh, 0.f);
    o2.y = fmaxf(bfu(v.z >> 16)     * s + sh, 0.f);
    o2.z = fmaxf(bfu(v.w & 0xffffu) * s + sh, 0.f);
    o2.w = fmaxf(bfu(v.w >> 16)     * s + sh, 0.f);
    *(float4*)(out + (size_t)i * 8)     = o1;
    *(float4*)(out + (size_t)i * 8 + 4) = o2;
  }
}

extern "C" void kernel_launch(void* const* d_in, const int* in_sizes, int n_in,
                              void* d_out, int out_size, void* d_ws, size_t ws_size,
                              hipStream_t stream) {
  const float* x   = (const float*)d_in[0];
  const float* dww = (const float*)d_in[1];
  // d_in[2] = dw_b : cancels inside BN1 -> unused
  const float* g1  = (const float*)d_in[3];
  const float* b1  = (const float*)d_in[4];
  const float* pww = (const float*)d_in[5];
  // d_in[6] = pw_b : cancels inside BN2 -> unused
  const float* g2  = (const float*)d_in[7];
  const float* b2  = (const float*)d_in[8];
  float* out = (float*)d_out;
  char* ws = (char*)d_ws;
  float* stats1 = (float*)(ws + WS_STATS1);
  float* scale1 = (float*)(ws + WS_SCALE1);
  float* shift1 = (float*)(ws + WS_SHIFT1);
  float* stats2 = (float*)(ws + WS_STATS2);
  bf16* wbf = (bf16*)(ws + WS_WBF);
  bf16* yt  = (bf16*)(ws + WS_YT);
  bf16* zbf = (bf16*)(ws + WS_ZBF);

  hipMemsetAsync(d_ws, 0, 8192, stream);  // zero stats1 + stats2
  k1_dwstats<<<BATCH * CIN, 256, 0, stream>>>(x, dww, stats1);
  k2_finalize1<<<513, 256, 0, stream>>>(stats1, g1, b1, pww, scale1, shift1, wbf);
  k3_normT<<<BATCH * 56 * 4, 256, 0, stream>>>(x, dww, scale1, shift1, yt);
  k4_gemm<<<3136, 256, 0, stream>>>(wbf, yt, zbf, stats2);
  k5_bn2<<<2048, 256, 0, stream>>>(zbf, stats2, g2, b2, out);
}

// Round 7
// 499.931 us; speedup vs baseline: 1.0680x; 1.0053x over previous
//
#include <hip/hip_runtime.h>
#include <hip/hip_bf16.h>
#include <stdint.h>

// DepthSepConv2d: x(32,256,56,56) -> dw3x3(reflect) -> BN1 -> ReLU -> pw 256->512 -> BN2 -> ReLU
// R6: BN2 stats via Gram trick (sum z = W.ybar, sum z^2 = w^T G w, G = Y Y^T) so the
// main GEMM fuses BN2+ReLU and writes fp32 d_out directly. No z materialization, no K5.
// Order: K1 stats1 | K2 fin1+w->bf16 | K3 conv+BN1+ReLU->y_t bf16 | Kg Gram+ybar |
//        K2c fin2 | K4 GEMM+BN2+ReLU->out
// dw_b / pw_b cancel exactly inside their BN -> skipped.

#define CIN   256
#define COUT  512
#define BATCH 32
#define HH    56
#define WWID  56
#define HWSZ  3136
#define NTOT  100352
#define NHWF  100352.0f
#define EPSV  1e-5f

typedef __bf16 bf16;
typedef __bf16 bf16x8 __attribute__((ext_vector_type(8)));
typedef float  f32x4  __attribute__((ext_vector_type(4)));

// ws layout (bytes)
#define WS_STATS1   0          // 512 f
#define WS_SCALE1   2048       // 256 f
#define WS_SHIFT1   3072       // 256 f
#define WS_YSUM     4096       // 256 f
#define WS_S2       5120       // 512 f
#define WS_T2       7168       // 512 f (ends 9216)
#define WS_G        16384      // 256*256 f = 256 KiB (ends 278528)
#define WS_WBF      278528     // 512*256 bf16 = 256 KiB (ends 540672)
#define WS_YT       540672     // 100352*256 bf16 (ends 51,920,896)

__device__ __forceinline__ void gload16(const void* g, void* l) {
  __builtin_amdgcn_global_load_lds((const __attribute__((address_space(1))) void*)g,
                                   (__attribute__((address_space(3))) void*)l, 16, 0, 0);
}

// ---------------- K1: depthwise conv (no bias) -> per-channel sum/sumsq ----------------
__global__ __launch_bounds__(256) void k1_dwstats(const float* __restrict__ x,
                                                  const float* __restrict__ dww,
                                                  float* __restrict__ stats1) {
  __shared__ float plane[HWSZ];
  __shared__ float red[8];
  int bid = blockIdx.x;
  int c = bid & (CIN - 1);
  int b = bid >> 8;
  const float4* xp4 = (const float4*)(x + ((size_t)(b * CIN + c)) * HWSZ);
  float4* pl4 = (float4*)plane;
  for (int i = threadIdx.x; i < HWSZ / 4; i += 256) pl4[i] = xp4[i];
  float w9[9];
#pragma unroll
  for (int q = 0; q < 9; ++q) w9[q] = dww[c * 9 + q];
  __syncthreads();
  float s = 0.f, sq = 0.f;
  for (int p = threadIdx.x; p < HWSZ; p += 256) {
    int h = p / WWID;
    int w = p - h * WWID;
    float acc = 0.f;
#pragma unroll
    for (int dy = 0; dy < 3; ++dy) {
      int hh = h - 1 + dy;
      hh = hh < 0 ? 1 : (hh > 55 ? 54 : hh);   // reflect pad=1
#pragma unroll
      for (int dx = 0; dx < 3; ++dx) {
        int ww2 = w - 1 + dx;
        ww2 = ww2 < 0 ? 1 : (ww2 > 55 ? 54 : ww2);
        acc += w9[dy * 3 + dx] * plane[hh * WWID + ww2];
      }
    }
    s += acc; sq += acc * acc;
  }
#pragma unroll
  for (int m = 1; m < 64; m <<= 1) { s += __shfl_xor(s, m); sq += __shfl_xor(sq, m); }
  int wv = threadIdx.x >> 6;
  if ((threadIdx.x & 63) == 0) { red[wv] = s; red[4 + wv] = sq; }
  __syncthreads();
  if (threadIdx.x == 0) {
    atomicAdd(&stats1[c],        red[0] + red[1] + red[2] + red[3]);
    atomicAdd(&stats1[CIN + c],  red[4] + red[5] + red[6] + red[7]);
  }
}

// ---------------- K2: finalize BN1 + convert pw_w to bf16 ----------------
__global__ __launch_bounds__(256) void k2_finalize1(const float* __restrict__ stats1,
                                                    const float* __restrict__ g1,
                                                    const float* __restrict__ b1,
                                                    const float* __restrict__ pww,
                                                    float* __restrict__ scale1,
                                                    float* __restrict__ shift1,
                                                    bf16* __restrict__ wbf) {
  int blk = blockIdx.x, t = threadIdx.x;
  if (blk == 0) {
    float mean = stats1[t] * (1.0f / NHWF);
    float var  = stats1[CIN + t] * (1.0f / NHWF) - mean * mean;
    float sc = g1[t] * rsqrtf(var + EPSV);
    scale1[t] = sc;
    shift1[t] = b1[t] - mean * sc;
  } else {
    int o = blk - 1;
    wbf[o * CIN + t] = (bf16)pww[o * CIN + t];
  }
}

// ---------------- K3: conv + BN1 + ReLU -> y_t[r = b*HWSZ+hw][c] bf16 ----------------
__global__ __launch_bounds__(256) void k3_normT(const float* __restrict__ x,
                                                const float* __restrict__ dww,
                                                const float* __restrict__ scale1,
                                                const float* __restrict__ shift1,
                                                bf16* __restrict__ yt) {
  __shared__ float xt[64][3][58];
  __shared__ __align__(16) bf16 outt[56][64];
  int bid = blockIdx.x;
  int cg = bid & 3;
  int h  = (bid >> 2) % 56;
  int b  = bid / 224;
  int c0 = cg * 64;
  int hr0 = (h == 0) ? 1 : h - 1;
  int hr2 = (h == 55) ? 54 : h + 1;
  for (int idx = threadIdx.x; idx < 64 * 3 * 56; idx += 256) {
    int c = idx / 168;
    int rem = idx - c * 168;
    int r = rem / 56;
    int w = rem - r * 56;
    int hr = (r == 0) ? hr0 : ((r == 1) ? h : hr2);
    xt[c][r][w + 1] = x[((size_t)((b * CIN + c0 + c) * HH + hr)) * WWID + w];
  }
  __syncthreads();
  if (threadIdx.x < 192) {
    int c = threadIdx.x / 3, r = threadIdx.x % 3;
    xt[c][r][0]  = xt[c][r][2];
    xt[c][r][57] = xt[c][r][55];
  }
  __syncthreads();
  int c  = threadIdx.x >> 2;
  int wq = threadIdx.x & 3;
  float w9[9];
#pragma unroll
  for (int q = 0; q < 9; ++q) w9[q] = dww[(c0 + c) * 9 + q];
  float sc = scale1[c0 + c], sh = shift1[c0 + c];
  for (int w = wq; w < 56; w += 4) {
    float acc = 0.f;
#pragma unroll
    for (int r = 0; r < 3; ++r) {
      const float* row = &xt[c][r][w];
      acc += w9[r * 3 + 0] * row[0] + w9[r * 3 + 1] * row[1] + w9[r * 3 + 2] * row[2];
    }
    float v = fmaxf(acc * sc + sh, 0.f);
    outt[w][c] = (bf16)v;
  }
  __syncthreads();
  for (int idx = threadIdx.x; idx < 56 * 8; idx += 256) {
    int w = idx >> 3, part = idx & 7;
    uint4 v = *(const uint4*)(&outt[w][part * 8]);
    *(uint4*)(yt + ((size_t)(b * HWSZ + h * WWID + w)) * CIN + c0 + part * 8) = v;
  }
}

// ---------------- Kg: Gram G[c][c'] = sum_r y[r][c] y[r][c'] + ybar ----------------
// 392 blocks = 98 r-chunks(1024) x 4 quadrant jobs (qa,qb). LDS holds y^T[c 256][r 64]
// bf16 with XOR-swizzled r-groups of 8 (rs = (r&7)|(((r>>3)^(c&7))<<3)) -> 16B frag reads.
__global__ __launch_bounds__(256) void kg_gram(const bf16* __restrict__ yt,
                                               float* __restrict__ G,
                                               float* __restrict__ ysum) {
  __shared__ __align__(16) unsigned short yTl[256 * 64];   // 32 KiB
  int bid = blockIdx.x;
  int job = bid & 3;
  int chunk = bid >> 2;                 // 98 chunks of 1024 rows
  int qa = job >> 1, qb = job & 1;
  int tid = threadIdx.x;
  int wv = tid >> 6, l = tid & 63;
  int wm = wv >> 1, wn = wv & 1;
  f32x4 acc[4][4];
#pragma unroll
  for (int mi = 0; mi < 4; ++mi)
#pragma unroll
    for (int ni = 0; ni < 4; ++ni) acc[mi][ni] = (f32x4){0.f, 0.f, 0.f, 0.f};
  float ys = 0.f;
  int r_loc = tid >> 2;                 // 0..63
  int ci0 = tid & 3;
  int rs_k[8];
#pragma unroll
  for (int k = 0; k < 8; ++k) rs_k[k] = (r_loc & 7) | (((r_loc >> 3) ^ k) << 3);

  for (int it = 0; it < 16; ++it) {
    const unsigned short* src = (const unsigned short*)yt + ((size_t)chunk * 1024 + it * 64 + r_loc) * CIN;
#pragma unroll
    for (int u = 0; u < 8; ++u) {
      int c0 = (ci0 + u * 4) * 8;
      unsigned short v8[8];
      *(uint4*)v8 = *(const uint4*)(src + c0);
#pragma unroll
      for (int k = 0; k < 8; ++k) yTl[(c0 + k) * 64 + rs_k[k]] = v8[k];
    }
    __syncthreads();
#pragma unroll
    for (int kk = 0; kk < 2; ++kk) {
      bf16x8 af[4], bfr[4];
      int rc = kk * 4 + (l >> 4);
#pragma unroll
      for (int mi = 0; mi < 4; ++mi) {
        int c = qa * 128 + wm * 64 + mi * 16 + (l & 15);
        af[mi] = *(const bf16x8*)(yTl + c * 64 + ((rc ^ (c & 7)) << 3));
      }
#pragma unroll
      for (int ni = 0; ni < 4; ++ni) {
        int c = qb * 128 + wn * 64 + ni * 16 + (l & 15);
        bfr[ni] = *(const bf16x8*)(yTl + c * 64 + ((rc ^ (c & 7)) << 3));
      }
#pragma unroll
      for (int mi = 0; mi < 4; ++mi)
#pragma unroll
        for (int ni = 0; ni < 4; ++ni)
          acc[mi][ni] = __builtin_amdgcn_mfma_f32_16x16x32_bf16(af[mi], bfr[ni], acc[mi][ni], 0, 0, 0);
    }
    if (job == 0) {                     // ybar duty: row tid = channel tid (swizzle is bijective per row)
      const bf16* row = (const bf16*)(yTl + tid * 64);
#pragma unroll
      for (int i = 0; i < 64; ++i) ys += (float)row[i];
    }
    __syncthreads();
  }
#pragma unroll
  for (int mi = 0; mi < 4; ++mi)
#pragma unroll
    for (int ni = 0; ni < 4; ++ni)
#pragma unroll
      for (int j = 0; j < 4; ++j) {
        int m = qa * 128 + wm * 64 + mi * 16 + (l >> 4) * 4 + j;
        int n = qb * 128 + wn * 64 + ni * 16 + (l & 15);
        atomicAdd(&G[m * 256 + n], acc[mi][ni][j]);
      }
  if (job == 0) atomicAdd(&ysum[tid], ys);
}

// ---------------- K2c: finalize BN2 from Gram: s2/t2 per o ----------------
__global__ __launch_bounds__(256) void k2c_fin2(const float* __restrict__ G,
                                                const float* __restrict__ ysum,
                                                const bf16* __restrict__ wbf,
                                                const float* __restrict__ g2,
                                                const float* __restrict__ b2,
                                                float* __restrict__ s2,
                                                float* __restrict__ t2) {
  __shared__ float wl[256];
  __shared__ float red[8];
  int o = blockIdx.x, t = threadIdx.x;
  wl[t] = (float)wbf[o * 256 + t];
  __syncthreads();
  float gw = 0.f;
  for (int c = 0; c < 256; ++c) gw += G[c * 256 + t] * wl[c];   // (G^T w)[t], coalesced
  float msq_p  = gw * wl[t];
  float mean_p = wl[t] * ysum[t];
#pragma unroll
  for (int m = 1; m < 64; m <<= 1) { msq_p += __shfl_xor(msq_p, m); mean_p += __shfl_xor(mean_p, m); }
  int wv = t >> 6;
  if ((t & 63) == 0) { red[wv] = msq_p; red[4 + wv] = mean_p; }
  __syncthreads();
  if (t == 0) {
    float msq  = (red[0] + red[1] + red[2] + red[3]) * (1.0f / NHWF);
    float mean = (red[4] + red[5] + red[6] + red[7]) * (1.0f / NHWF);
    float var  = msq - mean * mean;
    float sc = g2[o] * rsqrtf(var + EPSV);
    s2[o] = sc;
    t2[o] = b2[o] - mean * sc;
  }
}

// ---------------- K4: GEMM + fused BN2 + ReLU -> out fp32 ----------------
// Tile 128(o) x 128(r), BK=64, 4 waves 2x2, wave 64x64 = 4x4 frags.
// chunk-XOR swizzle (ck ^ (row&7)) on pre-swizzled global source + ds_read.
__global__ __launch_bounds__(256) void k4_gemm(const bf16* __restrict__ wbf,
                                               const bf16* __restrict__ yt,
                                               const float* __restrict__ s2,
                                               const float* __restrict__ t2,
                                               float* __restrict__ out) {
  __shared__ __align__(16) unsigned char LDSBUF[32768];  // A[0:16K) B[16K:32K)
  __shared__ float s2l[128], t2l[128];
  unsigned char* Als = LDSBUF;
  unsigned char* Bls = LDSBUF + 16384;
  int wg = blockIdx.x;
  int newid = (wg & 7) * 392 + (wg >> 3);   // XCD-chunked swizzle (3136 % 8 == 0)
  int mt    = newid & 3;
  int ntile = newid >> 2;
  int tid = threadIdx.x;
  int wv = tid >> 6, l = tid & 63;
  int wm = wv >> 1, wn = wv & 1;
  if (tid < 128) { s2l[tid] = s2[mt * 128 + tid]; t2l[tid] = t2[mt * 128 + tid]; }
  f32x4 acc[4][4];
#pragma unroll
  for (int mi = 0; mi < 4; ++mi)
#pragma unroll
    for (int ni = 0; ni < 4; ++ni) acc[mi][ni] = (f32x4){0.f, 0.f, 0.f, 0.f};
  const char* wb = (const char*)wbf;
  const char* yb = (const char*)yt + (size_t)ntile * 128 * CIN * 2;

  for (int k0 = 0; k0 < 256; k0 += 64) {
#pragma unroll
    for (int i = 0; i < 4; ++i) {
      int q = i * 256 + wv * 64 + l;
      int row = q >> 3, pp = q & 7;
      int cc = pp ^ (row & 7);
      gload16(wb + ((size_t)(mt * 128 + row) * CIN + k0) * 2 + cc * 16,
              Als + i * 4096 + wv * 1024);
      gload16(yb + ((size_t)row * CIN + k0) * 2 + cc * 16,
              Bls + i * 4096 + wv * 1024);
    }
    __syncthreads();
#pragma unroll
    for (int kk = 0; kk < 2; ++kk) {
      bf16x8 af[4], bfr[4];
#pragma unroll
      for (int mi = 0; mi < 4; ++mi) {
        int row = wm * 64 + mi * 16 + (l & 15);
        int ck = kk * 4 + (l >> 4);
        af[mi] = *(const bf16x8*)(Als + row * 128 + ((ck ^ (row & 7)) << 4));
      }
#pragma unroll
      for (int ni = 0; ni < 4; ++ni) {
        int row = wn * 64 + ni * 16 + (l & 15);
        int ck = kk * 4 + (l >> 4);
        bfr[ni] = *(const bf16x8*)(Bls + row * 128 + ((ck ^ (row & 7)) << 4));
      }
#pragma unroll
      for (int mi = 0; mi < 4; ++mi)
#pragma unroll
        for (int ni = 0; ni < 4; ++ni)
          acc[mi][ni] = __builtin_amdgcn_mfma_f32_16x16x32_bf16(af[mi], bfr[ni], acc[mi][ni], 0, 0, 0);
    }
    __syncthreads();
  }

  // epilogue: BN2 + ReLU, direct fp32 stores (16-lane 64B aligned segments)
#pragma unroll
  for (int mi = 0; mi < 4; ++mi)
#pragma unroll
    for (int ni = 0; ni < 4; ++ni)
#pragma unroll
      for (int j = 0; j < 4; ++j) {
        int ol = wm * 64 + mi * 16 + (l >> 4) * 4 + j;
        int r_flat = ntile * 128 + wn * 64 + ni * 16 + (l & 15);
        int b  = r_flat / HWSZ;            // 16-runs never straddle (3136 % 16 == 0)
        int hw = r_flat - b * HWSZ;
        float v = fmaxf(acc[mi][ni][j] * s2l[ol] + t2l[ol], 0.f);
        out[((size_t)(b * COUT + mt * 128 + ol)) * HWSZ + hw] = v;
      }
}

extern "C" void kernel_launch(void* const* d_in, const int* in_sizes, int n_in,
                              void* d_out, int out_size, void* d_ws, size_t ws_size,
                              hipStream_t stream) {
  const float* x   = (const float*)d_in[0];
  const float* dww = (const float*)d_in[1];
  // d_in[2] = dw_b : cancels inside BN1 -> unused
  const float* g1  = (const float*)d_in[3];
  const float* b1  = (const float*)d_in[4];
  const float* pww = (const float*)d_in[5];
  // d_in[6] = pw_b : cancels inside BN2 -> unused
  const float* g2  = (const float*)d_in[7];
  const float* b2  = (const float*)d_in[8];
  float* out = (float*)d_out;
  char* ws = (char*)d_ws;
  float* stats1 = (float*)(ws + WS_STATS1);
  float* scale1 = (float*)(ws + WS_SCALE1);
  float* shift1 = (float*)(ws + WS_SHIFT1);
  float* ysum   = (float*)(ws + WS_YSUM);
  float* s2     = (float*)(ws + WS_S2);
  float* t2     = (float*)(ws + WS_T2);
  float* G      = (float*)(ws + WS_G);
  bf16* wbf = (bf16*)(ws + WS_WBF);
  bf16* yt  = (bf16*)(ws + WS_YT);

  hipMemsetAsync(d_ws, 0, WS_WBF, stream);  // zero stats1 + ysum + G
  k1_dwstats<<<BATCH * CIN, 256, 0, stream>>>(x, dww, stats1);
  k2_finalize1<<<513, 256, 0, stream>>>(stats1, g1, b1, pww, scale1, shift1, wbf);
  k3_normT<<<BATCH * 56 * 4, 256, 0, stream>>>(x, dww, scale1, shift1, yt);
  kg_gram<<<392, 256, 0, stream>>>(yt, G, ysum);
  k2c_fin2<<<COUT, 256, 0, stream>>>(G, ysum, wbf, g2, b2, s2, t2);
  k4_gemm<<<3136, 256, 0, stream>>>(wbf, yt, s2, t2, out);
}

// Round 10
// 408.562 us; speedup vs baseline: 1.3068x; 1.2236x over previous
//
#include <hip/hip_runtime.h>
#include <hip/hip_bf16.h>
#include <stdint.h>

// DepthSepConv2d: x(32,256,56,56) -> dw3x3(reflect) -> BN1 -> ReLU -> pw 256->512 -> BN2 -> ReLU
// R8b: conv computed ONCE (K1' emits y_raw bf16 + stats1); K3' = normalize+transpose only.
// Kg staging vectorized (b64 LDS writes). BN2 via Gram trick unchanged.
// Order: K1' stats1+yraw | K2 fin1+w->bf16 | K3' norm+T->yt | Kg Gram+ybar | k2c fin2 |
//        K4 GEMM+BN2+ReLU->out.  dw_b / pw_b cancel inside their BN -> skipped.
// (R8 fix: K3' grid is exactly 6272 = BATCH*196; the R8 expression launched 7168 and
//  blocks >=6272 would have written past yt into yraw -- race/corruption.)

#define CIN   256
#define COUT  512
#define BATCH 32
#define HH    56
#define WWID  56
#define HWSZ  3136
#define NTOT  100352
#define NHWF  100352.0f
#define EPSV  1e-5f

typedef __bf16 bf16;
typedef __bf16 bf16x8 __attribute__((ext_vector_type(8)));
typedef float  f32x4  __attribute__((ext_vector_type(4)));

// ws layout (bytes)
#define WS_STATS1   0          // 512 f
#define WS_SCALE1   2048       // 256 f
#define WS_SHIFT1   3072       // 256 f
#define WS_YSUM     4096       // 256 f
#define WS_S2       5120       // 512 f
#define WS_T2       7168       // 512 f (ends 9216)
#define WS_G        16384      // 256*256 f = 256 KiB (ends 278528)
#define WS_WBF      278528     // 512*256 bf16 = 256 KiB (ends 540672)
#define WS_YT       540672     // 100352*256 bf16 (ends 51,920,896)
#define WS_YRAW     51920896   // 32*256*3136 bf16 = 51,380,224 (ends 103,301,120)

__device__ __forceinline__ void gload16(const void* g, void* l) {
  __builtin_amdgcn_global_load_lds((const __attribute__((address_space(1))) void*)g,
                                   (__attribute__((address_space(3))) void*)l, 16, 0, 0);
}
__device__ __forceinline__ float bfu(unsigned int u16) {
  unsigned int x = u16 << 16;
  return __builtin_bit_cast(float, x);
}

// ---------------- K1': depthwise conv (no bias) -> y_raw bf16 + per-channel sum/sumsq ----------------
__global__ __launch_bounds__(256) void k1_conv_stats(const float* __restrict__ x,
                                                     const float* __restrict__ dww,
                                                     float* __restrict__ stats1,
                                                     bf16* __restrict__ yraw) {
  __shared__ float plane[HWSZ];
  __shared__ float red[8];
  int bid = blockIdx.x;
  int c = bid & (CIN - 1);
  int b = bid >> 8;
  const float4* xp4 = (const float4*)(x + ((size_t)(b * CIN + c)) * HWSZ);
  float4* pl4 = (float4*)plane;
  for (int i = threadIdx.x; i < HWSZ / 4; i += 256) pl4[i] = xp4[i];
  float w9[9];
#pragma unroll
  for (int q = 0; q < 9; ++q) w9[q] = dww[c * 9 + q];
  __syncthreads();
  bf16* yout = yraw + ((size_t)(b * CIN + c)) * HWSZ;
  float s = 0.f, sq = 0.f;
  for (int p = threadIdx.x; p < HWSZ; p += 256) {
    int h = p / WWID;
    int w = p - h * WWID;
    float acc = 0.f;
#pragma unroll
    for (int dy = 0; dy < 3; ++dy) {
      int hh = h - 1 + dy;
      hh = hh < 0 ? 1 : (hh > 55 ? 54 : hh);   // reflect pad=1
#pragma unroll
      for (int dx = 0; dx < 3; ++dx) {
        int ww2 = w - 1 + dx;
        ww2 = ww2 < 0 ? 1 : (ww2 > 55 ? 54 : ww2);
        acc += w9[dy * 3 + dx] * plane[hh * WWID + ww2];
      }
    }
    s += acc; sq += acc * acc;
    yout[p] = (bf16)acc;                       // stats stay fp32-exact; only y_raw rounded
  }
#pragma unroll
  for (int m = 1; m < 64; m <<= 1) { s += __shfl_xor(s, m); sq += __shfl_xor(sq, m); }
  int wv = threadIdx.x >> 6;
  if ((threadIdx.x & 63) == 0) { red[wv] = s; red[4 + wv] = sq; }
  __syncthreads();
  if (threadIdx.x == 0) {
    atomicAdd(&stats1[c],        red[0] + red[1] + red[2] + red[3]);
    atomicAdd(&stats1[CIN + c],  red[4] + red[5] + red[6] + red[7]);
  }
}

// ---------------- K2: finalize BN1 + convert pw_w to bf16 ----------------
__global__ __launch_bounds__(256) void k2_finalize1(const float* __restrict__ stats1,
                                                    const float* __restrict__ g1,
                                                    const float* __restrict__ b1,
                                                    const float* __restrict__ pww,
                                                    float* __restrict__ scale1,
                                                    float* __restrict__ shift1,
                                                    bf16* __restrict__ wbf) {
  int blk = blockIdx.x, t = threadIdx.x;
  if (blk == 0) {
    float mean = stats1[t] * (1.0f / NHWF);
    float var  = stats1[CIN + t] * (1.0f / NHWF) - mean * mean;
    float sc = g1[t] * rsqrtf(var + EPSV);
    scale1[t] = sc;
    shift1[t] = b1[t] - mean * sc;
  } else {
    int o = blk - 1;
    wbf[o * CIN + t] = (bf16)pww[o * CIN + t];
  }
}

// ---------------- K3': BN1+ReLU + transpose: y_raw[b][c][hw] -> yt[r][c] bf16 ----------------
// 64c x 64hw tiles; LDS stride 66 spreads banks; both global sides 128B-contiguous.
__global__ __launch_bounds__(256) void k3_normT(const bf16* __restrict__ yraw,
                                                const float* __restrict__ scale1,
                                                const float* __restrict__ shift1,
                                                bf16* __restrict__ yt) {
  __shared__ unsigned short tl[64 * 66];
  int bid = blockIdx.x;
  int hwt = bid % 49;
  int cg  = (bid / 49) & 3;
  int b   = bid / 196;
  int t = threadIdx.x;
  int cl = t >> 3, hq = t & 7;
#pragma unroll
  for (int hh = 0; hh < 2; ++hh) {
    int c_l = cl + hh * 32;
    int c = cg * 64 + c_l;
    float sc = scale1[c], sh = shift1[c];
    unsigned short v8[8];
    *(uint4*)v8 = *(const uint4*)((const unsigned short*)yraw +
                                  ((size_t)(b * CIN + c)) * HWSZ + hwt * 64 + hq * 8);
#pragma unroll
    for (int j = 0; j < 8; ++j) {
      float v = fmaxf(bfu(v8[j]) * sc + sh, 0.f);
      bf16 hb = (bf16)v;
      tl[c_l * 66 + hq * 8 + j] = *(unsigned short*)&hb;
    }
  }
  __syncthreads();
  int rl = t >> 3, cq = t & 7;
#pragma unroll
  for (int hh = 0; hh < 2; ++hh) {
    int r_l = rl + hh * 32;
    unsigned short o8[8];
#pragma unroll
    for (int k = 0; k < 8; ++k) o8[k] = tl[(cq * 8 + k) * 66 + r_l];
    *(uint4*)((unsigned short*)yt + ((size_t)(b * HWSZ + hwt * 64 + r_l)) * CIN + cg * 64 + cq * 8) =
        *(uint4*)o8;
  }
}

// ---------------- Kg: Gram G[c][c'] = sum_r y[r][c] y[r][c'] + ybar ----------------
// 392 blocks = 98 r-chunks(1024) x 4 quadrant jobs. LDS y^T[c 256][r 64] bf16, XOR-swizzled
// r-octets (rs = (r&7) | (((r>>3)^(c&7))<<3)). Staging: coalesced uint4 loads + b64 LDS writes.
__global__ __launch_bounds__(256) void kg_gram(const bf16* __restrict__ yt,
                                               float* __restrict__ G,
                                               float* __restrict__ ysum) {
  __shared__ __align__(16) unsigned short yTl[256 * 64];   // 32 KiB
  int bid = blockIdx.x;
  int job = bid & 3;
  int chunk = bid >> 2;                 // 98 chunks of 1024 rows
  int qa = job >> 1, qb = job & 1;
  int tid = threadIdx.x;
  int wv = tid >> 6, l = tid & 63;
  int wm = wv >> 1, wn = wv & 1;
  f32x4 acc[4][4];
#pragma unroll
  for (int mi = 0; mi < 4; ++mi)
#pragma unroll
    for (int ni = 0; ni < 4; ++ni) acc[mi][ni] = (f32x4){0.f, 0.f, 0.f, 0.f};
  float ys = 0.f;
  int rq  = tid & 15;                   // r-quad: rows rq*4..rq*4+3
  int cgp = tid >> 4;                   // channel octet 0..15

  for (int it = 0; it < 16; ++it) {
    const unsigned short* srcb = (const unsigned short*)yt +
        ((size_t)chunk * 1024 + it * 64 + rq * 4) * CIN;
    unsigned short v[2][4][8];
#pragma unroll
    for (int u = 0; u < 2; ++u)
#pragma unroll
      for (int j = 0; j < 4; ++j)
        *(uint4*)v[u][j] = *(const uint4*)(srcb + (size_t)j * CIN + u * 128 + cgp * 8);
#pragma unroll
    for (int u = 0; u < 2; ++u)
#pragma unroll
      for (int k = 0; k < 8; ++k) {
        int c = u * 128 + cgp * 8 + k;                       // c&7 == k
        int addr = c * 64 + (((rq >> 1) ^ k) << 3) + (rq & 1) * 4;
        unsigned short o4[4] = {v[u][0][k], v[u][1][k], v[u][2][k], v[u][3][k]};
        *(unsigned long long*)(yTl + addr) = *(const unsigned long long*)o4;
      }
    __syncthreads();
#pragma unroll
    for (int kk = 0; kk < 2; ++kk) {
      bf16x8 af[4], bfr[4];
      int rc = kk * 4 + (l >> 4);
#pragma unroll
      for (int mi = 0; mi < 4; ++mi) {
        int c = qa * 128 + wm * 64 + mi * 16 + (l & 15);
        af[mi] = *(const bf16x8*)(yTl + c * 64 + ((rc ^ (c & 7)) << 3));
      }
#pragma unroll
      for (int ni = 0; ni < 4; ++ni) {
        int c = qb * 128 + wn * 64 + ni * 16 + (l & 15);
        bfr[ni] = *(const bf16x8*)(yTl + c * 64 + ((rc ^ (c & 7)) << 3));
      }
#pragma unroll
      for (int mi = 0; mi < 4; ++mi)
#pragma unroll
        for (int ni = 0; ni < 4; ++ni)
          acc[mi][ni] = __builtin_amdgcn_mfma_f32_16x16x32_bf16(af[mi], bfr[ni], acc[mi][ni], 0, 0, 0);
    }
    if (job == 0) {                     // ybar: swizzle is bijective within each c-row
      const bf16* row = (const bf16*)(yTl + tid * 64);
#pragma unroll
      for (int i = 0; i < 64; ++i) ys += (float)row[i];
    }
    __syncthreads();
  }
#pragma unroll
  for (int mi = 0; mi < 4; ++mi)
#pragma unroll
    for (int ni = 0; ni < 4; ++ni)
#pragma unroll
      for (int j = 0; j < 4; ++j) {
        int m = qa * 128 + wm * 64 + mi * 16 + (l >> 4) * 4 + j;
        int n = qb * 128 + wn * 64 + ni * 16 + (l & 15);
        atomicAdd(&G[m * 256 + n], acc[mi][ni][j]);
      }
  if (job == 0) atomicAdd(&ysum[tid], ys);
}

// ---------------- K2c: finalize BN2 from Gram: s2/t2 per o ----------------
__global__ __launch_bounds__(256) void k2c_fin2(const float* __restrict__ G,
                                                const float* __restrict__ ysum,
                                                const bf16* __restrict__ wbf,
                                                const float* __restrict__ g2,
                                                const float* __restrict__ b2,
                                                float* __restrict__ s2,
                                                float* __restrict__ t2) {
  __shared__ float wl[256];
  __shared__ float red[8];
  int o = blockIdx.x, t = threadIdx.x;
  wl[t] = (float)wbf[o * 256 + t];
  __syncthreads();
  float gw = 0.f;
  for (int c = 0; c < 256; ++c) gw += G[c * 256 + t] * wl[c];   // G symmetric
  float msq_p  = gw * wl[t];
  float mean_p = wl[t] * ysum[t];
#pragma unroll
  for (int m = 1; m < 64; m <<= 1) { msq_p += __shfl_xor(msq_p, m); mean_p += __shfl_xor(mean_p, m); }
  int wv = t >> 6;
  if ((t & 63) == 0) { red[wv] = msq_p; red[4 + wv] = mean_p; }
  __syncthreads();
  if (t == 0) {
    float msq  = (red[0] + red[1] + red[2] + red[3]) * (1.0f / NHWF);
    float mean = (red[4] + red[5] + red[6] + red[7]) * (1.0f / NHWF);
    float var  = msq - mean * mean;
    float sc = g2[o] * rsqrtf(var + EPSV);
    s2[o] = sc;
    t2[o] = b2[o] - mean * sc;
  }
}

// ---------------- K4: GEMM + fused BN2 + ReLU -> out fp32 ----------------
__global__ __launch_bounds__(256) void k4_gemm(const bf16* __restrict__ wbf,
                                               const bf16* __restrict__ yt,
                                               const float* __restrict__ s2,
                                               const float* __restrict__ t2,
                                               float* __restrict__ out) {
  __shared__ __align__(16) unsigned char LDSBUF[32768];  // A[0:16K) B[16K:32K)
  __shared__ float s2l[128], t2l[128];
  unsigned char* Als = LDSBUF;
  unsigned char* Bls = LDSBUF + 16384;
  int wg = blockIdx.x;
  int newid = (wg & 7) * 392 + (wg >> 3);   // XCD-chunked swizzle (3136 % 8 == 0)
  int mt    = newid & 3;
  int ntile = newid >> 2;
  int tid = threadIdx.x;
  int wv = tid >> 6, l = tid & 63;
  int wm = wv >> 1, wn = wv & 1;
  if (tid < 128) { s2l[tid] = s2[mt * 128 + tid]; t2l[tid] = t2[mt * 128 + tid]; }
  f32x4 acc[4][4];
#pragma unroll
  for (int mi = 0; mi < 4; ++mi)
#pragma unroll
    for (int ni = 0; ni < 4; ++ni) acc[mi][ni] = (f32x4){0.f, 0.f, 0.f, 0.f};
  const char* wb = (const char*)wbf;
  const char* yb = (const char*)yt + (size_t)ntile * 128 * CIN * 2;

  for (int k0 = 0; k0 < 256; k0 += 64) {
#pragma unroll
    for (int i = 0; i < 4; ++i) {
      int q = i * 256 + wv * 64 + l;
      int row = q >> 3, pp = q & 7;
      int cc = pp ^ (row & 7);
      gload16(wb + ((size_t)(mt * 128 + row) * CIN + k0) * 2 + cc * 16,
              Als + i * 4096 + wv * 1024);
      gload16(yb + ((size_t)row * CIN + k0) * 2 + cc * 16,
              Bls + i * 4096 + wv * 1024);
    }
    __syncthreads();
#pragma unroll
    for (int kk = 0; kk < 2; ++kk) {
      bf16x8 af[4], bfr[4];
#pragma unroll
      for (int mi = 0; mi < 4; ++mi) {
        int row = wm * 64 + mi * 16 + (l & 15);
        int ck = kk * 4 + (l >> 4);
        af[mi] = *(const bf16x8*)(Als + row * 128 + ((ck ^ (row & 7)) << 4));
      }
#pragma unroll
      for (int ni = 0; ni < 4; ++ni) {
        int row = wn * 64 + ni * 16 + (l & 15);
        int ck = kk * 4 + (l >> 4);
        bfr[ni] = *(const bf16x8*)(Bls + row * 128 + ((ck ^ (row & 7)) << 4));
      }
#pragma unroll
      for (int mi = 0; mi < 4; ++mi)
#pragma unroll
        for (int ni = 0; ni < 4; ++ni)
          acc[mi][ni] = __builtin_amdgcn_mfma_f32_16x16x32_bf16(af[mi], bfr[ni], acc[mi][ni], 0, 0, 0);
    }
    __syncthreads();
  }

  // epilogue: BN2 + ReLU, direct fp32 stores (16-lane 64B aligned segments)
#pragma unroll
  for (int mi = 0; mi < 4; ++mi)
#pragma unroll
    for (int ni = 0; ni < 4; ++ni)
#pragma unroll
      for (int j = 0; j < 4; ++j) {
        int ol = wm * 64 + mi * 16 + (l >> 4) * 4 + j;
        int r_flat = ntile * 128 + wn * 64 + ni * 16 + (l & 15);
        int b  = r_flat / HWSZ;            // 16-runs never straddle (3136 % 16 == 0)
        int hw = r_flat - b * HWSZ;
        float v = fmaxf(acc[mi][ni][j] * s2l[ol] + t2l[ol], 0.f);
        out[((size_t)(b * COUT + mt * 128 + ol)) * HWSZ + hw] = v;
      }
}

extern "C" void kernel_launch(void* const* d_in, const int* in_sizes, int n_in,
                              void* d_out, int out_size, void* d_ws, size_t ws_size,
                              hipStream_t stream) {
  const float* x   = (const float*)d_in[0];
  const float* dww = (const float*)d_in[1];
  // d_in[2] = dw_b : cancels inside BN1 -> unused
  const float* g1  = (const float*)d_in[3];
  const float* b1  = (const float*)d_in[4];
  const float* pww = (const float*)d_in[5];
  // d_in[6] = pw_b : cancels inside BN2 -> unused
  const float* g2  = (const float*)d_in[7];
  const float* b2  = (const float*)d_in[8];
  float* out = (float*)d_out;
  char* ws = (char*)d_ws;
  float* stats1 = (float*)(ws + WS_STATS1);
  float* scale1 = (float*)(ws + WS_SCALE1);
  float* shift1 = (float*)(ws + WS_SHIFT1);
  float* ysum   = (float*)(ws + WS_YSUM);
  float* s2     = (float*)(ws + WS_S2);
  float* t2     = (float*)(ws + WS_T2);
  float* G      = (float*)(ws + WS_G);
  bf16* wbf  = (bf16*)(ws + WS_WBF);
  bf16* yt   = (bf16*)(ws + WS_YT);
  bf16* yraw = (bf16*)(ws + WS_YRAW);

  hipMemsetAsync(d_ws, 0, WS_WBF, stream);  // zero stats1 + ysum + G
  k1_conv_stats<<<BATCH * CIN, 256, 0, stream>>>(x, dww, stats1, yraw);
  k2_finalize1<<<513, 256, 0, stream>>>(stats1, g1, b1, pww, scale1, shift1, wbf);
  k3_normT<<<6272, 256, 0, stream>>>(yraw, scale1, shift1, yt);   // exactly BATCH*196
  kg_gram<<<392, 256, 0, stream>>>(yt, G, ysum);
  k2c_fin2<<<COUT, 256, 0, stream>>>(G, ysum, wbf, g2, b2, s2, t2);
  k4_gemm<<<3136, 256, 0, stream>>>(wbf, yt, s2, t2, out);
}